// Round 7
// baseline (689.815 us; speedup 1.0000x reference)
//
#include <hip/hip_runtime.h>
#include <hip/hip_bf16.h>

typedef __attribute__((ext_vector_type(8))) __bf16 bf16x8;
typedef __attribute__((ext_vector_type(4))) float f32x4;
typedef __attribute__((ext_vector_type(16))) float f32x16;
typedef __attribute__((ext_vector_type(4))) unsigned int u32x4;

#define DIM 1024
#define NHEADS 16
#define HDIM 64
#define BATCH 4
#define SEQ 2048
#define ROWS (BATCH * SEQ) /* 8192 */
#define SCL 0.18033688011112042f /* 0.125 * log2(e) */

__device__ inline unsigned short f2bf(float f) {
    __hip_bfloat16 h = __float2bfloat16(f);
    return *reinterpret_cast<unsigned short*>(&h);
}

// pack two floats to bf16x2 (RNE) -- v_cvt_pk_bf16_f32 on gfx950
__device__ inline unsigned int packbf2(float a, float b) {
    unsigned short ua = __builtin_bit_cast(unsigned short, (__bf16)a);
    unsigned short ub = __builtin_bit_cast(unsigned short, (__bf16)b);
    return (unsigned int)ua | ((unsigned int)ub << 16);
}

typedef const __attribute__((address_space(1))) unsigned int* gas_ptr;
typedef __attribute__((address_space(3))) unsigned int* las_ptr;
__device__ inline void gload16(const void* g, void* l) {
    __builtin_amdgcn_global_load_lds((gas_ptr)g, (las_ptr)l, 16, 0, 0);
}

// ---------------- cast fp32 -> bf16 (4 elems/thread) ----------------
__global__ __launch_bounds__(256) void cast_f32_bf16(const float* __restrict__ in,
                                                     unsigned short* __restrict__ out,
                                                     int n4) {
    int i = blockIdx.x * 256 + threadIdx.x;
    if (i < n4) {
        float4 v = ((const float4*)in)[i];
        ushort4 o;
        o.x = f2bf(v.x); o.y = f2bf(v.y); o.z = f2bf(v.z); o.w = f2bf(v.w);
        ((ushort4*)out)[i] = o;
    }
}

// ------------- transpose + cast: in[R][C] fp32 -> out[C][R] bf16 -------------
// rows with orow < srows get scaled by scl (folds softmax scale into W_qkv Q cols)
__global__ __launch_bounds__(256) void transpose_cast(const float* __restrict__ in,
                                                      unsigned short* __restrict__ out,
                                                      int R, int C, int srows, float scl) {
    __shared__ float tile[32][33];
    int c0 = blockIdx.x * 32, r0 = blockIdx.y * 32;
    int tx = threadIdx.x & 31, ty = threadIdx.x >> 5; // 32 x 8
#pragma unroll
    for (int i = 0; i < 32; i += 8) {
        int r = r0 + ty + i, c = c0 + tx;
        tile[ty + i][tx] = in[(size_t)r * C + c];
    }
    __syncthreads();
#pragma unroll
    for (int i = 0; i < 32; i += 8) {
        int orow = c0 + ty + i, oc = r0 + tx;
        float v = tile[tx][ty + i];
        if (orow < srows) v *= scl;
        out[(size_t)orow * R + oc] = f2bf(v);
    }
}

// ---------------- GEMM: C = A * Bt^T + bias ----------------
// BK=64 as two 32-chunks (keeps 64B LDS rows conflict-free + wave-linear DMA).
// bf16 path splits: cols [0,1024) -> Cq, cols [1024,N) -> Ckv. fp32 path: Cf.
__global__ __launch_bounds__(256) void gemm_bt_bias(const unsigned short* __restrict__ A,
                                                    const unsigned short* __restrict__ Bt,
                                                    const float* __restrict__ bias,
                                                    unsigned short* __restrict__ Cq,
                                                    unsigned short* __restrict__ Ckv,
                                                    float* __restrict__ Cf,
                                                    int M, int N, int K, int qcols) {
    __shared__ unsigned short As[2][128 * 32];
    __shared__ unsigned short Bs[2][128 * 32];
    const int tid = threadIdx.x;
    const int lane = tid & 63, wave = tid >> 6;
    const int wm = (wave >> 1) * 64, wn = (wave & 1) * 64;
    const int rowA = blockIdx.y * 128, rowB = blockIdx.x * 128;
    const int fr = lane & 15, fo = (lane >> 4) * 8;

    f32x4 acc[4][4] = {};

    for (int k0 = 0; k0 < K; k0 += 64) {
#pragma unroll
        for (int kc = 0; kc < 2; kc++) {
#pragma unroll
            for (int c = 0; c < 2; c++) {
                int o = c * 4096 + tid * 16; // byte offset in 8KB chunk
                int r = o >> 6, cb = o & 63; // 64 B per row (32 bf16)
                int ldsb = c * 4096 + wave * 1024;
                gload16((const char*)A + ((size_t)(rowA + r) * K + k0 + kc * 32) * 2 + cb,
                        (char*)As[kc] + ldsb);
                gload16((const char*)Bt + ((size_t)(rowB + r) * K + k0 + kc * 32) * 2 + cb,
                        (char*)Bs[kc] + ldsb);
            }
        }
        __syncthreads();
#pragma unroll
        for (int kc = 0; kc < 2; kc++) {
            bf16x8 af[4], bfr[4];
#pragma unroll
            for (int i = 0; i < 4; i++) {
                af[i]  = *(const bf16x8*)(As[kc] + (wm + i * 16 + fr) * 32 + fo);
                bfr[i] = *(const bf16x8*)(Bs[kc] + (wn + i * 16 + fr) * 32 + fo);
            }
#pragma unroll
            for (int mi = 0; mi < 4; mi++)
#pragma unroll
                for (int ni = 0; ni < 4; ni++)
                    acc[mi][ni] = __builtin_amdgcn_mfma_f32_16x16x32_bf16(af[mi], bfr[ni],
                                                                          acc[mi][ni], 0, 0, 0);
        }
        __syncthreads();
    }

    // C/D layout (16x16): col = lane&15, row = (lane>>4)*4 + reg
    const int cn = lane & 15, cm = (lane >> 4) * 4;
    for (int ni = 0; ni < 4; ni++) {
        int gn = rowB + wn + ni * 16 + cn;
        float bv = bias[gn];
        if (gn < qcols) bv *= SCL;
        for (int mi = 0; mi < 4; mi++) {
#pragma unroll
            for (int r = 0; r < 4; r++) {
                int gm = rowA + wm + mi * 16 + cm + r;
                float v = acc[mi][ni][r] + bv;
                if (Cf) Cf[(size_t)gm * N + gn] = v;
                else if (gn < 1024) Cq[(size_t)gm * 1024 + gn] = f2bf(v);
                else Ckv[(size_t)gm * 2048 + (gn - 1024)] = f2bf(v);
            }
        }
    }
}

// -------- pack K,V into 32x32x16-fragment-major layouts --------
// Kp[bh][S/32][ks=4][lane=64][8]  A-frag: A[m=key(lane&31)][k=ks*16+(lane>>5)*8+j]
// Vp[bh][S/16][dt=2][lane=64][8]  B-frag with the S^T C-layout key permutation
//   baked in: B[k_virt=hh*8+j] maps to key (j&3)+8*(j>>2)+4*hh within the 16-key
//   group, so exp(S^T C-frag) registers ARE the PV A-frag (no LDS round-trip).
__global__ __launch_bounds__(256) void pack_kv(const unsigned short* __restrict__ KVb, // [8192][2048]
                                               unsigned short* __restrict__ Kp,
                                               unsigned short* __restrict__ Vp) {
    __shared__ unsigned short Kt[64][72];
    __shared__ unsigned short Vt[64][68];
    const int tid = threadIdx.x;
    const int s0 = blockIdx.x * 64;
    const int by = blockIdx.y;
    const int b = by >> 4, h = by & 15;
    const size_t rowbase = ((size_t)(b * SEQ + s0)) * 2048 + h * 64;
    const int c = (tid & 7) * 8, rr = tid >> 3; // 8 x 32
#pragma unroll
    for (int p = 0; p < 2; p++) {
        int row = p * 32 + rr;
        const unsigned short* src = KVb + rowbase + (size_t)row * 2048;
        uint4 kv = *(const uint4*)(src + c);
        uint4 vv = *(const uint4*)(src + 1024 + c);
        *(uint2*)&Kt[row][c]     = make_uint2(kv.x, kv.y);
        *(uint2*)&Kt[row][c + 4] = make_uint2(kv.z, kv.w);
        *(uint2*)&Vt[row][c]     = make_uint2(vv.x, vv.y);
        *(uint2*)&Vt[row][c + 4] = make_uint2(vv.z, vv.w);
    }
    __syncthreads();
    // K: 8 frags per 64-key block (ktl[2] x ks[4]) x 64 lanes = 512 x 16B
#pragma unroll
    for (int half = 0; half < 2; half++) {
        int f = half * 256 + tid;
        int ktl = f >> 8, ks = (f >> 6) & 3, ln = f & 63;
        int mm = ln & 31, hh = ln >> 5;
        uint4 d = *(const uint4*)&Kt[ktl * 32 + mm][ks * 16 + hh * 8];
        *(uint4*)(Kp + (((size_t)by * 64 + (s0 >> 5) + ktl) * 4 + ks) * 512 + ln * 8) = d;
    }
    // V: 8 frags per 64-key block (ksl[4] x dt[2]), permuted key order
#pragma unroll
    for (int half = 0; half < 2; half++) {
        int f = half * 256 + tid;
        int ksl = f >> 7, dt = (f >> 6) & 1, ln = f & 63;
        int mm = ln & 31, hh = ln >> 5;
        unsigned short tmp[8];
#pragma unroll
        for (int j = 0; j < 8; j++)
            tmp[j] = Vt[ksl * 16 + (j & 3) + 8 * (j >> 2) + 4 * hh][dt * 32 + mm];
        *(uint4*)(Vp + (((size_t)by * 128 + (s0 >> 4) + ksl) * 2 + dt) * 512 + ln * 8) =
            *(uint4*)tmp;
    }
}

// ---------------- flash attention v7: KV-split across 2 waves ----------------
// Block = 2 waves sharing 64 q; wave w handles keys [w*1024, +1024) with the
// zero-LDS zero-barrier v6 loop. No max-subtraction => partials combine by pure
// addition (one barrier at the end). XCD swizzle keeps each bh's K/V in one L2.
__global__ __launch_bounds__(128, 4) void attn_kernel(const unsigned short* __restrict__ Qb, // [8192][1024] prescaled
                                                      const unsigned short* __restrict__ Kp,
                                                      const unsigned short* __restrict__ Vp,
                                                      unsigned short* __restrict__ attnb) { // [8192][1024]
    __shared__ float Po[16 * 256]; // wave1 partial O: chunk c -> [c*256 + lane*4, +4)
    __shared__ float Pl[128];      // wave1 partial psum[2] per lane
    const int tid = threadIdx.x;
    const int lane = tid & 63, wave = tid >> 6;
    const int m31 = lane & 31, h = lane >> 5;

    // XCD swizzle: consecutive q-tiles of one bh land on one XCD
    const int gid = blockIdx.x;            // 0..2047
    const int slot = gid >> 3;             // 0..255
    const int by = (gid & 7) * 8 + (slot >> 5); // bh
    const int qt5 = slot & 31;             // q-tile (64 q each)
    const int b = by >> 4;
    const int bS = b * SEQ, hcol = (by & 15) * HDIM;
    const int q0 = qt5 * 64;

    // Q B-frags: qf[qt][ks]: B[k=ks*16+h*8+j][n=q0+qt*32+m31]
    bf16x8 qf[2][4];
#pragma unroll
    for (int qt = 0; qt < 2; qt++)
#pragma unroll
        for (int ks = 0; ks < 4; ks++)
            qf[qt][ks] = *(const bf16x8*)(Qb + (size_t)(bS + q0 + qt * 32 + m31) * 1024 +
                                          hcol + ks * 16 + h * 8);

    f32x16 oacc[2][2] = {}; // [qt][dt]: C row=q, col=d=dt*32+m31
    float psum[2] = {0.f, 0.f};

    const unsigned short* kbase = Kp + (size_t)by * 64 * 2048 + lane * 8;
    const unsigned short* vbase = Vp + (size_t)by * 128 * 1024 + lane * 8;

    const int ku0 = wave * 32; // 32 key-units of 32 keys each per wave
#pragma unroll 2
    for (int ki = 0; ki < 32; ki++) {
        int ku = ku0 + ki;
        const unsigned short* kp = kbase + (size_t)ku * 2048;
        bf16x8 kf[4];
#pragma unroll
        for (int ks = 0; ks < 4; ks++) kf[ks] = *(const bf16x8*)(kp + ks * 512);
        bf16x8 vf[2][2];
#pragma unroll
        for (int ks = 0; ks < 2; ks++) {
            const unsigned short* vp = vbase + ((size_t)ku * 2 + ks) * 1024;
            vf[ks][0] = *(const bf16x8*)(vp);
            vf[ks][1] = *(const bf16x8*)(vp + 512);
        }
#pragma unroll
        for (int qt = 0; qt < 2; qt++) {
            f32x16 cfrag = {};
#pragma unroll
            for (int ks = 0; ks < 4; ks++)
                cfrag = __builtin_amdgcn_mfma_f32_32x32x16_bf16(kf[ks], qf[qt][ks],
                                                                cfrag, 0, 0, 0);
            // exp2 + pack; packed regs = PV A-frag (keys permuted to match Vp)
            unsigned int pk[8];
            float ls = 0.f;
#pragma unroll
            for (int p = 0; p < 8; p++) {
                float e0 = __builtin_amdgcn_exp2f(cfrag[2 * p]);
                float e1 = __builtin_amdgcn_exp2f(cfrag[2 * p + 1]);
                ls += e0 + e1;
                pk[p] = packbf2(e0, e1);
            }
            psum[qt] += ls;
            u32x4 lo = {pk[0], pk[1], pk[2], pk[3]};
            u32x4 hi = {pk[4], pk[5], pk[6], pk[7]};
            bf16x8 pa0 = __builtin_bit_cast(bf16x8, lo); // keys [ku*32, +16) permuted
            bf16x8 pa1 = __builtin_bit_cast(bf16x8, hi); // keys [ku*32+16, +16)
            oacc[qt][0] = __builtin_amdgcn_mfma_f32_32x32x16_bf16(pa0, vf[0][0], oacc[qt][0], 0, 0, 0);
            oacc[qt][1] = __builtin_amdgcn_mfma_f32_32x32x16_bf16(pa0, vf[0][1], oacc[qt][1], 0, 0, 0);
            oacc[qt][0] = __builtin_amdgcn_mfma_f32_32x32x16_bf16(pa1, vf[1][0], oacc[qt][0], 0, 0, 0);
            oacc[qt][1] = __builtin_amdgcn_mfma_f32_32x32x16_bf16(pa1, vf[1][1], oacc[qt][1], 0, 0, 0);
        }
    }

    // wave 1 parks its partial (O, l) in LDS
    if (wave == 1) {
#pragma unroll
        for (int qt = 0; qt < 2; qt++)
#pragma unroll
            for (int dt = 0; dt < 2; dt++)
#pragma unroll
                for (int c = 0; c < 4; c++) {
                    f32x4 v = {oacc[qt][dt][c * 4 + 0], oacc[qt][dt][c * 4 + 1],
                               oacc[qt][dt][c * 4 + 2], oacc[qt][dt][c * 4 + 3]};
                    *(f32x4*)&Po[(qt * 8 + dt * 4 + c) * 256 + lane * 4] = v;
                }
        *(float2*)&Pl[lane * 2] = make_float2(psum[0], psum[1]);
    }
    __syncthreads();
    if (wave == 0) {
#pragma unroll
        for (int qt = 0; qt < 2; qt++)
#pragma unroll
            for (int dt = 0; dt < 2; dt++)
#pragma unroll
                for (int c = 0; c < 4; c++) {
                    f32x4 v = *(const f32x4*)&Po[(qt * 8 + dt * 4 + c) * 256 + lane * 4];
#pragma unroll
                    for (int j = 0; j < 4; j++) oacc[qt][dt][c * 4 + j] += v[j];
                }
        float2 pl = *(const float2*)&Pl[lane * 2];
        psum[0] += pl.x; psum[1] += pl.y;

        // epilogue: l[q] = psum(h=0)+psum(h=1); C rows: row=(r&3)+8*(r>>2)+4h
#pragma unroll
        for (int qt = 0; qt < 2; qt++) {
            float lt = psum[qt] + __shfl_xor(psum[qt], 32, 64);
            float rl = 1.f / lt; // valid on lanes where m31 == q
#pragma unroll
            for (int r = 0; r < 16; r++) {
                int row = (r & 3) + 8 * (r >> 2) + 4 * h;
                float rlr = __shfl(rl, row, 64);
                size_t orow = (size_t)(bS + q0 + qt * 32 + row) * 1024 + hcol;
                attnb[orow + m31]      = f2bf(oacc[qt][0][r] * rlr);
                attnb[orow + 32 + m31] = f2bf(oacc[qt][1][r] * rlr);
            }
        }
    }
}

extern "C" void kernel_launch(void* const* d_in, const int* in_sizes, int n_in,
                              void* d_out, int out_size, void* d_ws, size_t ws_size,
                              hipStream_t stream) {
    const float* x      = (const float*)d_in[0]; // [4,2048,1024]
    const float* W_qkv  = (const float*)d_in[1]; // [1024,3072]
    const float* b_qkv  = (const float*)d_in[2]; // [3072]
    const float* W_proj = (const float*)d_in[3]; // [1024,1024]
    const float* b_proj = (const float*)d_in[4]; // [1024]
    float* out = (float*)d_out;                  // [4,2048,1024]

    char* ws = (char*)d_ws;
    // lifetimes: x_bf,WqkvT die after gemm1; KVb dies after pack; Kp aliases x_bf;
    // attnb aliases KVb. Peak 88 MiB.
    unsigned short* x_bf   = (unsigned short*)(ws);                // [0,16M)
    unsigned short* WqkvT  = (unsigned short*)(ws + 16777216);     // [16M,22M)
    unsigned short* Qb     = (unsigned short*)(ws + 23068672);     // [22M,38M)
    unsigned short* KVb    = (unsigned short*)(ws + 39845888);     // [38M,70M)
    unsigned short* Kp     = (unsigned short*)(ws);                // reuses x_bf
    unsigned short* Vp     = (unsigned short*)(ws + 73400320);     // [70M,86M)
    unsigned short* attnb  = (unsigned short*)(ws + 39845888);     // reuses KVb
    unsigned short* WprojT = (unsigned short*)(ws + 90177536);     // [86M,88M)

    // 1) casts / transposes (Q columns of W_qkv pre-scaled into exp2 domain)
    cast_f32_bf16<<<(ROWS * DIM / 4 + 255) / 256, 256, 0, stream>>>(x, x_bf, ROWS * DIM / 4);
    transpose_cast<<<dim3(3 * DIM / 32, DIM / 32), 256, 0, stream>>>(W_qkv, WqkvT, DIM, 3 * DIM, DIM, SCL);
    transpose_cast<<<dim3(DIM / 32, DIM / 32), 256, 0, stream>>>(W_proj, WprojT, DIM, DIM, 0, 1.f);

    // 2) qkv = x @ W_qkv + b_qkv  -> Qb (bf16, scaled) + KVb (bf16)
    gemm_bt_bias<<<dim3(3 * DIM / 128, ROWS / 128), 256, 0, stream>>>(
        x_bf, WqkvT, b_qkv, Qb, KVb, nullptr, ROWS, 3 * DIM, DIM, DIM);

    // 3) pack K,V into fragment-major layouts (x_bf dead; Kp reuses it)
    pack_kv<<<dim3(SEQ / 64, BATCH * NHEADS), 256, 0, stream>>>(KVb, Kp, Vp);

    // 4) attention (KVb dead; attnb reuses it): 64 q/block, KV split across 2 waves
    attn_kernel<<<dim3(64 * (SEQ / 64)), 128, 0, stream>>>(Qb, Kp, Vp, attnb);

    // 5) out = attn @ W_proj + b_proj (fp32 out)
    gemm_bt_bias<<<dim3(DIM / 128, ROWS / 128), 256, 0, stream>>>(
        attnb, WprojT, b_proj, nullptr, nullptr, out, ROWS, DIM, DIM, 0);
}

// Round 8
// 296.776 us; speedup vs baseline: 2.3244x; 2.3244x over previous
//
#include <hip/hip_runtime.h>
#include <hip/hip_bf16.h>

typedef __attribute__((ext_vector_type(8))) __bf16 bf16x8;
typedef __attribute__((ext_vector_type(4))) float f32x4;
typedef __attribute__((ext_vector_type(16))) float f32x16;
typedef __attribute__((ext_vector_type(4))) unsigned int u32x4;

#define DIM 1024
#define NHEADS 16
#define HDIM 64
#define BATCH 4
#define SEQ 2048
#define ROWS (BATCH * SEQ) /* 8192 */
#define SCL 0.18033688011112042f /* 0.125 * log2(e) */

__device__ inline unsigned short f2bf(float f) {
    __hip_bfloat16 h = __float2bfloat16(f);
    return *reinterpret_cast<unsigned short*>(&h);
}

// pack two floats to bf16x2 (RNE) -- v_cvt_pk_bf16_f32 on gfx950
__device__ inline unsigned int packbf2(float a, float b) {
    unsigned short ua = __builtin_bit_cast(unsigned short, (__bf16)a);
    unsigned short ub = __builtin_bit_cast(unsigned short, (__bf16)b);
    return (unsigned int)ua | ((unsigned int)ub << 16);
}

typedef const __attribute__((address_space(1))) unsigned int* gas_ptr;
typedef __attribute__((address_space(3))) unsigned int* las_ptr;
__device__ inline void gload16(const void* g, void* l) {
    __builtin_amdgcn_global_load_lds((gas_ptr)g, (las_ptr)l, 16, 0, 0);
}

// ---------------- cast fp32 -> bf16 (4 elems/thread) ----------------
__global__ __launch_bounds__(256) void cast_f32_bf16(const float* __restrict__ in,
                                                     unsigned short* __restrict__ out,
                                                     int n4) {
    int i = blockIdx.x * 256 + threadIdx.x;
    if (i < n4) {
        float4 v = ((const float4*)in)[i];
        ushort4 o;
        o.x = f2bf(v.x); o.y = f2bf(v.y); o.z = f2bf(v.z); o.w = f2bf(v.w);
        ((ushort4*)out)[i] = o;
    }
}

// ------------- transpose + cast: in[R][C] fp32 -> out[C][R] bf16 -------------
// rows with orow < srows get scaled by scl (folds softmax scale into W_qkv Q cols)
__global__ __launch_bounds__(256) void transpose_cast(const float* __restrict__ in,
                                                      unsigned short* __restrict__ out,
                                                      int R, int C, int srows, float scl) {
    __shared__ float tile[32][33];
    int c0 = blockIdx.x * 32, r0 = blockIdx.y * 32;
    int tx = threadIdx.x & 31, ty = threadIdx.x >> 5; // 32 x 8
#pragma unroll
    for (int i = 0; i < 32; i += 8) {
        int r = r0 + ty + i, c = c0 + tx;
        tile[ty + i][tx] = in[(size_t)r * C + c];
    }
    __syncthreads();
#pragma unroll
    for (int i = 0; i < 32; i += 8) {
        int orow = c0 + ty + i, oc = r0 + tx;
        float v = tile[tx][ty + i];
        if (orow < srows) v *= scl;
        out[(size_t)orow * R + oc] = f2bf(v);
    }
}

// ---------------- GEMM: C = A * Bt^T + bias ----------------
// BK=64 as two 32-chunks (keeps 64B LDS rows conflict-free + wave-linear DMA).
// bf16 path splits: cols [0,1024) -> Cq, cols [1024,N) -> Ckv. fp32 path: Cf.
__global__ __launch_bounds__(256) void gemm_bt_bias(const unsigned short* __restrict__ A,
                                                    const unsigned short* __restrict__ Bt,
                                                    const float* __restrict__ bias,
                                                    unsigned short* __restrict__ Cq,
                                                    unsigned short* __restrict__ Ckv,
                                                    float* __restrict__ Cf,
                                                    int M, int N, int K, int qcols) {
    __shared__ unsigned short As[2][128 * 32];
    __shared__ unsigned short Bs[2][128 * 32];
    const int tid = threadIdx.x;
    const int lane = tid & 63, wave = tid >> 6;
    const int wm = (wave >> 1) * 64, wn = (wave & 1) * 64;
    const int rowA = blockIdx.y * 128, rowB = blockIdx.x * 128;
    const int fr = lane & 15, fo = (lane >> 4) * 8;

    f32x4 acc[4][4] = {};

    for (int k0 = 0; k0 < K; k0 += 64) {
#pragma unroll
        for (int kc = 0; kc < 2; kc++) {
#pragma unroll
            for (int c = 0; c < 2; c++) {
                int o = c * 4096 + tid * 16; // byte offset in 8KB chunk
                int r = o >> 6, cb = o & 63; // 64 B per row (32 bf16)
                int ldsb = c * 4096 + wave * 1024;
                gload16((const char*)A + ((size_t)(rowA + r) * K + k0 + kc * 32) * 2 + cb,
                        (char*)As[kc] + ldsb);
                gload16((const char*)Bt + ((size_t)(rowB + r) * K + k0 + kc * 32) * 2 + cb,
                        (char*)Bs[kc] + ldsb);
            }
        }
        __syncthreads();
#pragma unroll
        for (int kc = 0; kc < 2; kc++) {
            bf16x8 af[4], bfr[4];
#pragma unroll
            for (int i = 0; i < 4; i++) {
                af[i]  = *(const bf16x8*)(As[kc] + (wm + i * 16 + fr) * 32 + fo);
                bfr[i] = *(const bf16x8*)(Bs[kc] + (wn + i * 16 + fr) * 32 + fo);
            }
#pragma unroll
            for (int mi = 0; mi < 4; mi++)
#pragma unroll
                for (int ni = 0; ni < 4; ni++)
                    acc[mi][ni] = __builtin_amdgcn_mfma_f32_16x16x32_bf16(af[mi], bfr[ni],
                                                                          acc[mi][ni], 0, 0, 0);
        }
        __syncthreads();
    }

    // C/D layout (16x16): col = lane&15, row = (lane>>4)*4 + reg
    const int cn = lane & 15, cm = (lane >> 4) * 4;
    for (int ni = 0; ni < 4; ni++) {
        int gn = rowB + wn + ni * 16 + cn;
        float bv = bias[gn];
        if (gn < qcols) bv *= SCL;
        for (int mi = 0; mi < 4; mi++) {
#pragma unroll
            for (int r = 0; r < 4; r++) {
                int gm = rowA + wm + mi * 16 + cm + r;
                float v = acc[mi][ni][r] + bv;
                if (Cf) Cf[(size_t)gm * N + gn] = v;
                else if (gn < 1024) Cq[(size_t)gm * 1024 + gn] = f2bf(v);
                else Ckv[(size_t)gm * 2048 + (gn - 1024)] = f2bf(v);
            }
        }
    }
}

// -------- pack K,V into 32x32x16-fragment-major layouts --------
// Kp[bh][S/32][ks=4][lane=64][8]  A-frag: A[m=key(lane&31)][k=ks*16+(lane>>5)*8+j]
// Vp[bh][S/16][dt=2][lane=64][8]  B-frag with the S^T C-layout key permutation
//   baked in: B[k_virt=hh*8+j] maps to key (j&3)+8*(j>>2)+4*hh within the 16-key
//   group, so exp(S^T C-frag) registers ARE the PV A-frag (no LDS round-trip).
__global__ __launch_bounds__(256) void pack_kv(const unsigned short* __restrict__ KVb, // [8192][2048]
                                               unsigned short* __restrict__ Kp,
                                               unsigned short* __restrict__ Vp) {
    __shared__ unsigned short Kt[64][72];
    __shared__ unsigned short Vt[64][68];
    const int tid = threadIdx.x;
    const int s0 = blockIdx.x * 64;
    const int by = blockIdx.y;
    const int b = by >> 4, h = by & 15;
    const size_t rowbase = ((size_t)(b * SEQ + s0)) * 2048 + h * 64;
    const int c = (tid & 7) * 8, rr = tid >> 3; // 8 x 32
#pragma unroll
    for (int p = 0; p < 2; p++) {
        int row = p * 32 + rr;
        const unsigned short* src = KVb + rowbase + (size_t)row * 2048;
        uint4 kv = *(const uint4*)(src + c);
        uint4 vv = *(const uint4*)(src + 1024 + c);
        *(uint2*)&Kt[row][c]     = make_uint2(kv.x, kv.y);
        *(uint2*)&Kt[row][c + 4] = make_uint2(kv.z, kv.w);
        *(uint2*)&Vt[row][c]     = make_uint2(vv.x, vv.y);
        *(uint2*)&Vt[row][c + 4] = make_uint2(vv.z, vv.w);
    }
    __syncthreads();
    // K: 8 frags per 64-key block (ktl[2] x ks[4]) x 64 lanes = 512 x 16B
#pragma unroll
    for (int half = 0; half < 2; half++) {
        int f = half * 256 + tid;
        int ktl = f >> 8, ks = (f >> 6) & 3, ln = f & 63;
        int mm = ln & 31, hh = ln >> 5;
        uint4 d = *(const uint4*)&Kt[ktl * 32 + mm][ks * 16 + hh * 8];
        *(uint4*)(Kp + (((size_t)by * 64 + (s0 >> 5) + ktl) * 4 + ks) * 512 + ln * 8) = d;
    }
    // V: 8 frags per 64-key block (ksl[4] x dt[2]), permuted key order
#pragma unroll
    for (int half = 0; half < 2; half++) {
        int f = half * 256 + tid;
        int ksl = f >> 7, dt = (f >> 6) & 1, ln = f & 63;
        int mm = ln & 31, hh = ln >> 5;
        unsigned short tmp[8];
#pragma unroll
        for (int j = 0; j < 8; j++)
            tmp[j] = Vt[ksl * 16 + (j & 3) + 8 * (j >> 2) + 4 * hh][dt * 32 + mm];
        *(uint4*)(Vp + (((size_t)by * 128 + (s0 >> 4) + ksl) * 2 + dt) * 512 + ln * 8) =
            *(uint4*)tmp;
    }
}

// ---------------- flash attention v8: KV-split via grid, v6 loop intact ----------------
// Block = 4 waves: wave (qpair, ksplit) runs the zero-LDS zero-barrier v6 loop
// on 64 q and half the keys. Partials combine by pure addition (exp2 domain).
// 1024 blocks -> 4 blocks/CU -> 4 waves/SIMD at 128 VGPR. NO vgpr-capping
// launch bounds (R7: forcing 64 VGPR spilled accumulators -> 1 GB scratch traffic).
__global__ __launch_bounds__(256, 2) void attn_kernel(const unsigned short* __restrict__ Qb, // [8192][1024] prescaled
                                                      const unsigned short* __restrict__ Kp,
                                                      const unsigned short* __restrict__ Vp,
                                                      unsigned short* __restrict__ attnb) { // [8192][1024]
    __shared__ float Po[2][16 * 256]; // [qpair] partial O from ksplit=1 wave
    __shared__ float Pl[2][128];      // [qpair] partial psum[2] per lane
    const int tid = threadIdx.x;
    const int lane = tid & 63, wave = tid >> 6;
    const int qpair = wave >> 1, ksplit = wave & 1;
    const int m31 = lane & 31, h = lane >> 5;
    const int by = blockIdx.y;
    const int b = by >> 4;
    const int bS = b * SEQ, hcol = (by & 15) * HDIM;
    const int q0 = blockIdx.x * 128 + qpair * 64;

    // Q B-frags: qf[qt][ks]: B[k=ks*16+h*8+j][n=q0+qt*32+m31]
    bf16x8 qf[2][4];
#pragma unroll
    for (int qt = 0; qt < 2; qt++)
#pragma unroll
        for (int ks = 0; ks < 4; ks++)
            qf[qt][ks] = *(const bf16x8*)(Qb + (size_t)(bS + q0 + qt * 32 + m31) * 1024 +
                                          hcol + ks * 16 + h * 8);

    f32x16 oacc[2][2] = {}; // [qt][dt]: C row=q, col=d=dt*32+m31
    float psum[2] = {0.f, 0.f};

    const unsigned short* kbase = Kp + (size_t)by * 64 * 2048 + lane * 8;
    const unsigned short* vbase = Vp + (size_t)by * 128 * 1024 + lane * 8;

    const int ku0 = ksplit * 32; // each wave: 32 key-units of 32 keys
#pragma unroll 2
    for (int ki = 0; ki < 32; ki++) {
        int ku = ku0 + ki;
        const unsigned short* kp = kbase + (size_t)ku * 2048;
        bf16x8 kf[4];
#pragma unroll
        for (int ks = 0; ks < 4; ks++) kf[ks] = *(const bf16x8*)(kp + ks * 512);
        bf16x8 vf[2][2];
#pragma unroll
        for (int ks = 0; ks < 2; ks++) {
            const unsigned short* vp = vbase + ((size_t)ku * 2 + ks) * 1024;
            vf[ks][0] = *(const bf16x8*)(vp);
            vf[ks][1] = *(const bf16x8*)(vp + 512);
        }
#pragma unroll
        for (int qt = 0; qt < 2; qt++) {
            f32x16 cfrag = {};
#pragma unroll
            for (int ks = 0; ks < 4; ks++)
                cfrag = __builtin_amdgcn_mfma_f32_32x32x16_bf16(kf[ks], qf[qt][ks],
                                                                cfrag, 0, 0, 0);
            // exp2 + pack; packed regs = PV A-frag (keys permuted to match Vp)
            unsigned int pk[8];
            float ls = 0.f;
#pragma unroll
            for (int p = 0; p < 8; p++) {
                float e0 = __builtin_amdgcn_exp2f(cfrag[2 * p]);
                float e1 = __builtin_amdgcn_exp2f(cfrag[2 * p + 1]);
                ls += e0 + e1;
                pk[p] = packbf2(e0, e1);
            }
            psum[qt] += ls;
            u32x4 lo = {pk[0], pk[1], pk[2], pk[3]};
            u32x4 hi = {pk[4], pk[5], pk[6], pk[7]};
            bf16x8 pa0 = __builtin_bit_cast(bf16x8, lo); // keys [ku*32, +16) permuted
            bf16x8 pa1 = __builtin_bit_cast(bf16x8, hi); // keys [ku*32+16, +16)
            oacc[qt][0] = __builtin_amdgcn_mfma_f32_32x32x16_bf16(pa0, vf[0][0], oacc[qt][0], 0, 0, 0);
            oacc[qt][1] = __builtin_amdgcn_mfma_f32_32x32x16_bf16(pa0, vf[0][1], oacc[qt][1], 0, 0, 0);
            oacc[qt][0] = __builtin_amdgcn_mfma_f32_32x32x16_bf16(pa1, vf[1][0], oacc[qt][0], 0, 0, 0);
            oacc[qt][1] = __builtin_amdgcn_mfma_f32_32x32x16_bf16(pa1, vf[1][1], oacc[qt][1], 0, 0, 0);
        }
    }

    // ksplit=1 waves park partial (O, l) in LDS
    if (ksplit == 1) {
#pragma unroll
        for (int qt = 0; qt < 2; qt++)
#pragma unroll
            for (int dt = 0; dt < 2; dt++)
#pragma unroll
                for (int c = 0; c < 4; c++) {
                    f32x4 v = {oacc[qt][dt][c * 4 + 0], oacc[qt][dt][c * 4 + 1],
                               oacc[qt][dt][c * 4 + 2], oacc[qt][dt][c * 4 + 3]};
                    *(f32x4*)&Po[qpair][(qt * 8 + dt * 4 + c) * 256 + lane * 4] = v;
                }
        *(float2*)&Pl[qpair][lane * 2] = make_float2(psum[0], psum[1]);
    }
    __syncthreads();
    if (ksplit == 0) {
#pragma unroll
        for (int qt = 0; qt < 2; qt++)
#pragma unroll
            for (int dt = 0; dt < 2; dt++)
#pragma unroll
                for (int c = 0; c < 4; c++) {
                    f32x4 v = *(const f32x4*)&Po[qpair][(qt * 8 + dt * 4 + c) * 256 + lane * 4];
#pragma unroll
                    for (int j = 0; j < 4; j++) oacc[qt][dt][c * 4 + j] += v[j];
                }
        float2 pl = *(const float2*)&Pl[qpair][lane * 2];
        psum[0] += pl.x; psum[1] += pl.y;

        // epilogue: l[q] = psum(h=0)+psum(h=1); C rows: row=(r&3)+8*(r>>2)+4h
#pragma unroll
        for (int qt = 0; qt < 2; qt++) {
            float lt = psum[qt] + __shfl_xor(psum[qt], 32, 64);
            float rl = 1.f / lt; // valid on lanes where m31 == q
#pragma unroll
            for (int r = 0; r < 16; r++) {
                int row = (r & 3) + 8 * (r >> 2) + 4 * h;
                float rlr = __shfl(rl, row, 64);
                size_t orow = (size_t)(bS + q0 + qt * 32 + row) * 1024 + hcol;
                attnb[orow + m31]      = f2bf(oacc[qt][0][r] * rlr);
                attnb[orow + 32 + m31] = f2bf(oacc[qt][1][r] * rlr);
            }
        }
    }
}

extern "C" void kernel_launch(void* const* d_in, const int* in_sizes, int n_in,
                              void* d_out, int out_size, void* d_ws, size_t ws_size,
                              hipStream_t stream) {
    const float* x      = (const float*)d_in[0]; // [4,2048,1024]
    const float* W_qkv  = (const float*)d_in[1]; // [1024,3072]
    const float* b_qkv  = (const float*)d_in[2]; // [3072]
    const float* W_proj = (const float*)d_in[3]; // [1024,1024]
    const float* b_proj = (const float*)d_in[4]; // [1024]
    float* out = (float*)d_out;                  // [4,2048,1024]

    char* ws = (char*)d_ws;
    // lifetimes: x_bf,WqkvT die after gemm1; KVb dies after pack; Kp aliases x_bf;
    // attnb aliases KVb. Peak 88 MiB.
    unsigned short* x_bf   = (unsigned short*)(ws);                // [0,16M)
    unsigned short* WqkvT  = (unsigned short*)(ws + 16777216);     // [16M,22M)
    unsigned short* Qb     = (unsigned short*)(ws + 23068672);     // [22M,38M)
    unsigned short* KVb    = (unsigned short*)(ws + 39845888);     // [38M,70M)
    unsigned short* Kp     = (unsigned short*)(ws);                // reuses x_bf
    unsigned short* Vp     = (unsigned short*)(ws + 73400320);     // [70M,86M)
    unsigned short* attnb  = (unsigned short*)(ws + 39845888);     // reuses KVb
    unsigned short* WprojT = (unsigned short*)(ws + 90177536);     // [86M,88M)

    // 1) casts / transposes (Q columns of W_qkv pre-scaled into exp2 domain)
    cast_f32_bf16<<<(ROWS * DIM / 4 + 255) / 256, 256, 0, stream>>>(x, x_bf, ROWS * DIM / 4);
    transpose_cast<<<dim3(3 * DIM / 32, DIM / 32), 256, 0, stream>>>(W_qkv, WqkvT, DIM, 3 * DIM, DIM, SCL);
    transpose_cast<<<dim3(DIM / 32, DIM / 32), 256, 0, stream>>>(W_proj, WprojT, DIM, DIM, 0, 1.f);

    // 2) qkv = x @ W_qkv + b_qkv  -> Qb (bf16, scaled) + KVb (bf16)
    gemm_bt_bias<<<dim3(3 * DIM / 128, ROWS / 128), 256, 0, stream>>>(
        x_bf, WqkvT, b_qkv, Qb, KVb, nullptr, ROWS, 3 * DIM, DIM, DIM);

    // 3) pack K,V into fragment-major layouts (x_bf dead; Kp reuses it)
    pack_kv<<<dim3(SEQ / 64, BATCH * NHEADS), 256, 0, stream>>>(KVb, Kp, Vp);

    // 4) attention (KVb dead; attnb reuses it): 128 q/block, KV split across wave pairs
    attn_kernel<<<dim3(SEQ / 128, BATCH * NHEADS), 256, 0, stream>>>(Qb, Kp, Vp, attnb);

    // 5) out = attn @ W_proj + b_proj (fp32 out)
    gemm_bt_bias<<<dim3(DIM / 128, ROWS / 128), 256, 0, stream>>>(
        attnb, WprojT, b_proj, nullptr, nullptr, out, ROWS, DIM, DIM, 0);
}